// Round 1
// baseline (137.134 us; speedup 1.0000x reference)
//
#include <hip/hip_runtime.h>

#define Bn 16
#define Cn 64
#define Hn 128
#define Wn 128
#define HWn (Hn * Wn)

typedef __attribute__((ext_vector_type(8)))  short  short8;    // 8 bf16
typedef __attribute__((ext_vector_type(16))) float  floatx16;  // 32x32 C/D
typedef __attribute__((ext_vector_type(4)))  float  floatx4;
using int32x4 = int __attribute__((ext_vector_type(4)));

__device__ float
llvm_amdgcn_raw_buffer_load_fp32(int32x4 srsrc, int voffset, int soffset,
                                 int aux) __asm("llvm.amdgcn.raw.buffer.load.f32");
__device__ floatx4
llvm_amdgcn_raw_buffer_load_v4f32(int32x4 srsrc, int voffset, int soffset,
                                  int aux) __asm("llvm.amdgcn.raw.buffer.load.v4f32");

__device__ __forceinline__ int32x4 make_rsrc(const void* p, int bytes) {
    int32x4 r;
    r.x = (int)(unsigned)(uintptr_t)p;
    r.y = (int)((uintptr_t)p >> 32);   // stride=0
    r.z = bytes;                        // num_records
    r.w = 0x00020000;                   // raw dword SRD
    return r;
}

__device__ __forceinline__ unsigned short f2bf(float f) {  // RNE f32->bf16
    unsigned u = __float_as_uint(f);
    u += 0x7fffu + ((u >> 16) & 1u);
    return (unsigned short)(u >> 16);
}
__device__ __forceinline__ float lrelu(float v) { return v >= 0.f ? v : 0.1f * v; }

// ---------------------------------------------------------------------------
// Kernel-gen (R5 proven structure, unchanged). Outputs:
//   kernP[b][c][12]  fp32, taps 0..8 at [0..8], pad [9..11] (16B-aligned rows)
//   WcBF [o][c]      bf16 RNE (row-major, A-operand friendly)
// ---------------------------------------------------------------------------
__global__ __launch_bounds__(192)
void gen_kern6(const float* __restrict__ d,
               const float* __restrict__ Wk1,
               const float* __restrict__ Wk2,
               const float* __restrict__ Wc,
               float* __restrict__ kernP,            // ws: [16][64][12]
               unsigned short* __restrict__ WcBF) {  // ws: [64][64] bf16
    const int b = blockIdx.x;   // 16
    const int r = blockIdx.y;   // 3
    const int t = threadIdx.x;  // 192
    __shared__ float hid_s[64];

    if (t < 64) {
        const float4* __restrict__ w4 = (const float4*)(Wk1 + (size_t)t * 64);
        const float*  __restrict__ db = d + b * 64;
        float s0 = 0.f, s1 = 0.f, s2 = 0.f, s3 = 0.f;
        #pragma unroll
        for (int j = 0; j < 16; ++j) {
            const float4 wv = w4[j];
            s0 += db[4 * j + 0] * wv.x;
            s1 += db[4 * j + 1] * wv.y;
            s2 += db[4 * j + 2] * wv.z;
            s3 += db[4 * j + 3] * wv.w;
        }
        hid_s[t] = lrelu((s0 + s1) + (s2 + s3));
    }
    __syncthreads();

    {
        const int o = r * 192 + t;                   // 576 = 3*192
        const float4* __restrict__ w4 = (const float4*)(Wk2 + (size_t)o * 64);
        const float4* __restrict__ h4 = (const float4*)hid_s;
        float s0 = 0.f, s1 = 0.f, s2 = 0.f, s3 = 0.f;
        #pragma unroll
        for (int j = 0; j < 16; ++j) {
            const float4 wv = w4[j];
            const float4 hv = h4[j];
            s0 += hv.x * wv.x;
            s1 += hv.y * wv.y;
            s2 += hv.z * wv.z;
            s3 += hv.w * wv.w;
        }
        const int c = o / 9, tap = o - c * 9;
        kernP[b * 768 + c * 12 + tap] = (s0 + s1) + (s2 + s3);
    }

    if (b == 0 && r == 0) {
        for (int idx = t; idx < 4096; idx += 192)
            WcBF[idx] = f2bf(Wc[idx]);
    }
}

// ---------------------------------------------------------------------------
// Main fused conv, R7: latency-oriented restructure of the proven R6 kernel.
//   * LDS now carries FINISHED bf16 dw values [16ch][128px] (4 KB/group,
//     double-buffered = 8 KB) instead of 26 KB fp32 t-planes. The horizontal
//     halo (t0[p-1] / t2[p+1]) is resolved IN-REGISTER via 2 __shfl from the
//     px-octet neighbor lane; borders masked by (t&15)==0/15. Numerics are
//     bit-identical to R6 (same fp32 sums, same RNE point).
//   * LDS ops/thread/group: 30 -> 9 (1x ds_write_b128 + 8x ds_read_u16).
//     Write is per-wave linear (lane*16B) => conflict-free. Read uses XOR-32
//     px swizzle for ch&8 rows so kh=0/kh=1 lane halves hit disjoint 16-bank
//     sets (2 lanes/bank = free).
//   * One barrier per group (4 total vs 8): iter g reads buf[g&1], writes
//     buf[(g+1)&1], syncthreads. Next-group x loads are issued BEFORE the
//     LDS-read+MFMA phase and consumed after it (same iteration), so their
//     ~200-400cy L2 latency hides under the MFMA phase with plain
//     __syncthreads (no cross-barrier vmcnt games needed).
//   * LDS 26112 -> 8192 B: block residency wave-capped (8 blocks/CU) instead
//     of LDS-capped (6), grid = exactly 8 blocks/CU.
// ---------------------------------------------------------------------------
struct XK { floatx4 x[3][2]; };   // 3 rows x 8 px (all indices compile-time)

__device__ __forceinline__ void issue_x(XK& v, int32x4 rs, int c,
                                        const int* rofsB, int px0) {
    #pragma unroll
    for (int r = 0; r < 3; ++r) {
        const int vo = (c << 16) + rofsB[r] + px0 * 4;
        v.x[r][0] = llvm_amdgcn_raw_buffer_load_v4f32(rs, vo, 0, 0);
        v.x[r][1] = llvm_amdgcn_raw_buffer_load_v4f32(rs, vo + 16, 0, 0);
    }
}

__device__ __forceinline__ short8 compute_dw(const XK& v, const float* kp,
                                             int c, int lane, int tm) {
    const floatx4* k4 = (const floatx4*)(kp + c * 12);
    const floatx4 k0 = k4[0];                 // taps 0..3
    const floatx4 k1 = k4[1];                 // taps 4..7
    const float   k8 = ((const float*)k4)[8]; // tap 8

    float t0[8], t1[8], t2[8];                // column sums per dx
    #pragma unroll
    for (int i = 0; i < 8; ++i) {
        const float xr0 = (i < 4) ? v.x[0][0][i] : v.x[0][1][i - 4];
        const float xr1 = (i < 4) ? v.x[1][0][i] : v.x[1][1][i - 4];
        const float xr2 = (i < 4) ? v.x[2][0][i] : v.x[2][1][i - 4];
        t0[i] = k0.x * xr0 + k0.w * xr1 + k1.z * xr2; // taps 0,3,6
        t1[i] = k0.y * xr0 + k1.x * xr1 + k1.w * xr2; // taps 1,4,7
        t2[i] = k0.z * xr0 + k1.y * xr1 + k8   * xr2; // taps 2,5,8
    }
    // halo from px-octet neighbors (same wave: tm>0 => lane-1 same wave)
    float t0m = __shfl(t0[7], lane - 1, 64);  // left  neighbor's t0[px0-1]
    float t2p = __shfl(t2[0], lane + 1, 64);  // right neighbor's t2[px0+8]
    if (tm == 0)  t0m = 0.f;                  // px = -1  border
    if (tm == 15) t2p = 0.f;                  // px = 128 border

    float dw[8];
    dw[0] = t0m + t1[0] + t2[1];
    #pragma unroll
    for (int i = 1; i < 7; ++i) dw[i] = t0[i - 1] + t1[i] + t2[i + 1];
    dw[7] = t0[6] + t1[7] + t2p;

    short8 w8;
    #pragma unroll
    for (int i = 0; i < 8; ++i) w8[i] = (short)f2bf(lrelu(dw[i]));
    return w8;
}

__global__ __launch_bounds__(256)
void da_mfma3(const float* __restrict__ x,
              const float* __restrict__ kernP,
              const unsigned short* __restrict__ WcBF,
              const float* __restrict__ bc,
              float* __restrict__ out) {
    const int t    = threadIdx.x;
    const int lane = t & 63;
    const int wv   = t >> 6;            // wave 0..3 -> px tile
    const int col  = lane & 31;         // px within tile / A-B n,m index
    const int kh   = lane >> 5;         // k-half (8 ch)
    const int bx   = blockIdx.x;        // 128
    const int h    = ((bx & 7) << 4) | (bx >> 3);   // XCD-band swizzle
    const int b    = blockIdx.y;        // 16
    const int px   = wv * 32 + col;

    // staging mapping
    const int sch = t >> 4;             // 0..15 (channel within group)
    const int tm  = t & 15;
    const int px0 = tm * 8;             // 8-px octet

    // dw exchange buffers: [buf][ch][px] bf16, px XOR-32-swizzled for ch&8
    __shared__ unsigned short dwB[2][2048];   // 8 KB total

    // vertical row byte-offsets; border -> OOB sentinel (loads return 0)
    int rofsB[3];
    #pragma unroll
    for (int i = 0; i < 3; ++i) {
        const int hh = h + i - 1;
        rofsB[i] = (hh >= 0 && hh < Hn) ? hh * (Wn * 4) : 0x10000000;
    }

    const int32x4 rs = make_rsrc(x + (size_t)b * Cn * HWn, Cn * HWn * 4);
    const float* __restrict__ kp = kernP + b * 768;

    // acc init = bias (D row o = m*32 + (r&3)+8*(r>>2)+4*kh)
    floatx16 acc[2];
    #pragma unroll
    for (int m = 0; m < 2; ++m)
        #pragma unroll
        for (int r = 0; r < 16; ++r)
            acc[m][r] = bc[m * 32 + (r & 3) + 8 * (r >> 2) + 4 * kh];

    // ---- prologue: stage group 0 ----
    {
        XK cur;
        issue_x(cur, rs, sch, rofsB, px0);
        const short8 w8 = compute_dw(cur, kp, sch, lane, tm);
        *(short8*)&dwB[0][sch * 128 + (px0 ^ ((sch & 8) << 2))] = w8;
    }
    __syncthreads();

    // ---- pipelined group loop: 1 barrier/group ----
    #pragma unroll
    for (int g = 0; g < 4; ++g) {
        XK nxt;
        if (g < 3)                                   // issue next-group x now;
            issue_x(nxt, rs, (g + 1) * 16 + sch, rofsB, px0);  // consumed below

        // B-frag read: 8x ds_read_u16, banks balanced via XOR-32 swizzle
        short8 bfr;
        #pragma unroll
        for (int j = 0; j < 8; ++j) {
            const int cl = kh * 8 + j;
            bfr[j] = (short)dwB[g & 1][cl * 128 + (px ^ ((cl & 8) << 2))];
        }
        const short8 a0 = *(const short8*)(WcBF + (0 * 32 + col) * 64 + g * 16 + kh * 8);
        const short8 a1 = *(const short8*)(WcBF + (1 * 32 + col) * 64 + g * 16 + kh * 8);
        acc[0] = __builtin_amdgcn_mfma_f32_32x32x16_bf16(a0, bfr, acc[0], 0, 0, 0);
        acc[1] = __builtin_amdgcn_mfma_f32_32x32x16_bf16(a1, bfr, acc[1], 0, 0, 0);

        if (g < 3) {   // x(g+1) latency was hidden under ds_reads + MFMA
            const short8 w8 = compute_dw(nxt, kp, (g + 1) * 16 + sch, lane, tm);
            *(short8*)&dwB[(g + 1) & 1][sch * 128 + (px0 ^ ((sch & 8) << 2))] = w8;
            __syncthreads();
        }
    }

    // ---- STORE: full 128B lines (32 px contiguous per o-row) ----
    float* __restrict__ ob = out + (size_t)b * Cn * HWn + h * Wn + px;
    #pragma unroll
    for (int m = 0; m < 2; ++m)
        #pragma unroll
        for (int r = 0; r < 16; ++r) {
            const int o = m * 32 + (r & 3) + 8 * (r >> 2) + 4 * kh;
            ob[(size_t)o * HWn] = acc[m][r];
        }
}

// ---------------------------------------------------------------------------
extern "C" void kernel_launch(void* const* d_in, const int* in_sizes, int n_in,
                              void* d_out, int out_size, void* d_ws, size_t ws_size,
                              hipStream_t stream) {
    const float* x   = (const float*)d_in[0];
    const float* d   = (const float*)d_in[1];
    const float* Wk1 = (const float*)d_in[2];
    const float* Wk2 = (const float*)d_in[3];
    const float* Wc  = (const float*)d_in[4];
    const float* bc  = (const float*)d_in[5];
    float* out = (float*)d_out;
    float*          kernP = (float*)d_ws;                         // 16*768 fp32
    unsigned short* WcBF  = (unsigned short*)((float*)d_ws + Bn * 768); // 64*64 bf16

    gen_kern6<<<dim3(Bn, 3), dim3(192), 0, stream>>>(d, Wk1, Wk2, Wc, kernP, WcBF);
    da_mfma3<<<dim3(Hn, Bn), dim3(256), 0, stream>>>(x, kernP, WcBF, bc, out);
}